// Round 4
// baseline (176.824 us; speedup 1.0000x reference)
//
#include <hip/hip_runtime.h>
#include <hip/hip_bf16.h>

// MHA: B=4, N=1024, E=1024, H=16, d=64.  fp32 I/O, bf16 MFMA internals.
//
// Round 16: gemm_qkv rebuilt as counted-vmcnt deep pipeline (T3+T4 regime):
// BM=BN=256, 512 thr (8 waves 2Mx4N, acc[8][4]), K as 32 slots of BK=32 in a
// 4-slot LDS ring (128 KB dynamic, hipFuncSetAttribute), prefetch distance 3,
// s_waitcnt vmcnt(8) per iter (NEVER 0 in steady state), raw s_barrier (no
// compiler drain), 2x16-MFMA phases per slot with setprio.  Grid 192 (16x12,
// XCD-mapped, 1 block/CU).  Old 128x128 kernel kept as small-ws fallback.
// attn (r15 stage-ahead dbuf) and gemm_out (r14 64x128) unchanged.
//
// XOR-swizzled LDS rows: 64-col tiles use slot8 ^= row&7; 32-col (qkv8) tiles
// use slot4 ^= row&3.  Staging via global_load_lds(16B) with pre-swizzled
// per-lane GLOBAL source + linear LDS dest (both-sides rule, m104/m231).
//
// ws (40 MB fast path): [Qw 8M][Kw 8M][Vw 8M][xb/Ow 8M][Wqb][Wkb][Wvb][Wob]
// (2 MB each).  ws_size < 40 MB -> fp32-W fallback (deterministic branch).
//
// MFMA m89/m91 layouts: A-frag A[m=l&15][k=(l>>4)*8+j]; B-frag same addressing
// from row-major [n][k]; C/D col=l&15, row=(l>>4)*4+reg.

typedef __bf16 bf16x8 __attribute__((ext_vector_type(8)));
typedef __bf16 bf16x4 __attribute__((ext_vector_type(4)));
typedef float  f32x4  __attribute__((ext_vector_type(4)));

#define LOG2E 1.44269504f

__device__ __forceinline__ void glds16(const __bf16* g, __bf16* l) {
  __builtin_amdgcn_global_load_lds(
      (const __attribute__((address_space(1))) void*)g,
      (__attribute__((address_space(3))) void*)l, 16, 0, 0);
}

__global__ __launch_bounds__(256) void cvt_f32_bf16(const float* __restrict__ in,
                                                    __bf16* __restrict__ out, int n4) {
  int i = blockIdx.x * 256 + threadIdx.x;
  if (i < n4) {
    float4 v = *(const float4*)(in + (size_t)i * 4);
    bf16x4 b = {(__bf16)v.x, (__bf16)v.y, (__bf16)v.z, (__bf16)v.w};
    *(bf16x4*)(out + (size_t)i * 4) = b;
  }
}

// Fused conversion: x (1M float4) + Wq/Wk/Wv/Wo (256K float4 each).
__global__ __launch_bounds__(256) void cvt_all(const float* __restrict__ x,
                                               const float* __restrict__ Wq,
                                               const float* __restrict__ Wk,
                                               const float* __restrict__ Wv,
                                               const float* __restrict__ Wo,
                                               __bf16* __restrict__ xb,
                                               __bf16* __restrict__ Wqb,
                                               __bf16* __restrict__ Wkb,
                                               __bf16* __restrict__ Wvb,
                                               __bf16* __restrict__ Wob) {
  const int i = blockIdx.x * 256 + threadIdx.x;  // 0..2097151
  const float* src;
  __bf16* dst;
  int off;
  if (i < 1048576) {
    src = x; dst = xb; off = i;
  } else {
    const int j = i - 1048576;
    const int seg = j >> 18;  // 0..3
    off = j & 262143;
    src = (seg == 0) ? Wq : (seg == 1) ? Wk : (seg == 2) ? Wv : Wo;
    dst = (seg == 0) ? Wqb : (seg == 1) ? Wkb : (seg == 2) ? Wvb : Wob;
  }
  float4 v = *(const float4*)(src + (size_t)off * 4);
  bf16x4 b = {(__bf16)v.x, (__bf16)v.y, (__bf16)v.z, (__bf16)v.w};
  *(bf16x4*)(dst + (size_t)off * 4) = b;
}

// ---------------------------------------------------------------------------
// gemm_qkv8: fused QKV projection, deep-pipelined.
// C[4096, 3072] = x @ [Wq;Wk;Wv]^T, 256x256 tiles -> grid 192 (16m x 12n).
// XCD map: c=bid&7, t=bid>>3 (0..23): mb=c*2+(t&1) (0..15), nb=t>>1 (0..11)
// -> XCD c owns m-panels {2c, 2c+1} (A 1 MB L2-local), all nb.
// K: 32 slots of 32 cols; LDS ring of 4 slots (A 4x[256][32] + B same,
// 128 KB dynamic).  Prefetch slot s+3 during iter s; wait vmcnt(8) at iter
// start (slots s+1, s+2 = 8 loads stay in flight).  Raw s_barrier.
// Per slot: 2 phases x 16 MFMA (mt 0-3 / 4-7), B-frags register-reused.
// ---------------------------------------------------------------------------
__global__ __launch_bounds__(512, 2) void gemm_qkv8(const __bf16* __restrict__ A,
                                                    const __bf16* __restrict__ Wqp,
                                                    const __bf16* __restrict__ Wkp,
                                                    const __bf16* __restrict__ Wvp,
                                                    const float* __restrict__ bq,
                                                    const float* __restrict__ bk,
                                                    const float* __restrict__ bv,
                                                    __bf16* __restrict__ Qw,
                                                    __bf16* __restrict__ Kw,
                                                    __bf16* __restrict__ Vw) {
  extern __shared__ __attribute__((aligned(16))) __bf16 lds[];
  // A slots: lds + slot*8192            (slot = [256][32] bf16 = 16 KB)
  // B slots: lds + 32768 + slot*8192

  const int tid = threadIdx.x;
  const int lane = tid & 63;
  const int w = tid >> 6, wm = w >> 2, wn = w & 3;  // 2M x 4N waves
  const int l15 = lane & 15, lq = lane >> 4;

  const int bid = blockIdx.x;
  const int c = bid & 7, t = bid >> 3;  // t = 0..23
  const int mb = c * 2 + (t & 1);       // 0..15
  const int nb = t >> 1;                // 0..11
  const int m0 = mb * 256;
  const int n0g = nb * 256;
  const int z = n0g >> 10;              // tile never spans z (1024 % 256 == 0)
  const int n0l = n0g & 1023;

  const __bf16* Wz = (z == 0) ? Wqp : (z == 1) ? Wkp : Wvp;
  const float* bias = (z == 0) ? bq : (z == 1) ? bk : bv;
  __bf16* C = (z == 0) ? Qw : (z == 1) ? Kw : Vw;
  const float scale = (z == 0) ? LOG2E : 1.0f;

  // staging lane map: 512 lanes cover 128 rows x 64 B; 2 rounds per matrix.
  // LDS dest is LINEAR (tid*16 B); global source col pre-swizzled by row&3.
  const int srow = tid >> 2;                   // 0..127
  const int scs = tid & 3;                     // 16B slot in row
  const int sxor = (scs ^ (srow & 3)) * 8;     // source col (elems)
  const __bf16* Asrc = A + (size_t)(m0 + srow) * 1024 + sxor;
  const __bf16* Bsrc = Wz + (size_t)(n0l + srow) * 1024 + sxor;
  __bf16* AsD = lds + (size_t)tid * 8;           // + slot*8192 + half*4096
  __bf16* BsD = lds + 32768 + (size_t)tid * 8;

#define STAGE_A(slot, kk)                                            \
  do {                                                               \
    glds16(Asrc + (kk), AsD + (slot) * 8192);                        \
    glds16(Asrc + (kk) + 131072, AsD + (slot) * 8192 + 4096);        \
  } while (0)
#define STAGE_B(slot, kk)                                            \
  do {                                                               \
    glds16(Bsrc + (kk), BsD + (slot) * 8192);                        \
    glds16(Bsrc + (kk) + 131072, BsD + (slot) * 8192 + 4096);        \
  } while (0)

  // fragment read bases (reader XORs col-slot with row&3 = l15&3)
  const int axor = (lq ^ (l15 & 3)) * 8;
  const __bf16* aBase = lds + (wm * 128 + l15) * 32 + axor;          // + mt*512 + slot*8192
  const __bf16* bBase = lds + 32768 + (wn * 64 + l15) * 32 + axor;   // + nt*512 + slot*8192

  f32x4 acc[8][4] = {};

  // prologue: stage slots 0..2 (12 vmem instrs per wave, in slot order)
#pragma unroll
  for (int s = 0; s < 3; ++s) {
    STAGE_A(s, s * 32);
    STAGE_B(s, s * 32);
  }

  for (int s = 0; s < 32; ++s) {
    // wait: slot s landed; slots s+1, s+2 (8 loads) stay in flight
    if (s <= 29)
      asm volatile("s_waitcnt vmcnt(8)" ::: "memory");
    else if (s == 30)
      asm volatile("s_waitcnt vmcnt(4)" ::: "memory");
    else
      asm volatile("s_waitcnt vmcnt(0)" ::: "memory");
    __builtin_amdgcn_s_barrier();  // release slot s; protect ring slot (s+3)&3

    const int slot = s & 3;
    const __bf16* ap = aBase + slot * 8192;
    const __bf16* bp = bBase + slot * 8192;

    if (s + 3 < 32) STAGE_A((s + 3) & 3, (s + 3) * 32);

    bf16x8 bf[4], af[4];
#pragma unroll
    for (int nt = 0; nt < 4; ++nt) bf[nt] = *(const bf16x8*)(bp + nt * 512);
#pragma unroll
    for (int mt = 0; mt < 4; ++mt) af[mt] = *(const bf16x8*)(ap + mt * 512);
    __builtin_amdgcn_s_setprio(1);
#pragma unroll
    for (int mt = 0; mt < 4; ++mt)
#pragma unroll
      for (int nt = 0; nt < 4; ++nt)
        acc[mt][nt] = __builtin_amdgcn_mfma_f32_16x16x32_bf16(af[mt], bf[nt],
                                                              acc[mt][nt], 0, 0, 0);
    __builtin_amdgcn_s_setprio(0);

    __builtin_amdgcn_s_barrier();  // mid lockstep

    if (s + 3 < 32) STAGE_B((s + 3) & 3, (s + 3) * 32);
#pragma unroll
    for (int mt = 0; mt < 4; ++mt) af[mt] = *(const bf16x8*)(ap + (4 + mt) * 512);
    __builtin_amdgcn_s_setprio(1);
#pragma unroll
    for (int mt = 0; mt < 4; ++mt)
#pragma unroll
      for (int nt = 0; nt < 4; ++nt)
        acc[4 + mt][nt] = __builtin_amdgcn_mfma_f32_16x16x32_bf16(af[mt], bf[nt],
                                                                  acc[4 + mt][nt], 0, 0, 0);
    __builtin_amdgcn_s_setprio(0);
  }
#undef STAGE_A
#undef STAGE_B

  // epilogue (same mapping as 128x128 kernel, wave tile now 128x64)
#pragma unroll
  for (int mt = 0; mt < 8; ++mt) {
    const int mg_base = m0 + wm * 128 + mt * 16 + lq * 4;
    const int bb = mg_base >> 10, nr0 = mg_base & 1023;
#pragma unroll
    for (int nt = 0; nt < 4; ++nt) {
      const int nl = n0l + wn * 64 + nt * 16 + l15;
      const float bv = bias[nl];
      const int h = nl >> 6, dd = nl & 63;
      if (z != 2) {
#pragma unroll
        for (int rr = 0; rr < 4; ++rr) {
          const int mg = mg_base + rr;
          const size_t idx =
              ((size_t)(bb * 16 + h) << 16) + (size_t)(mg & 1023) * 64 + dd;
          C[idx] = (__bf16)((acc[mt][nt][rr] + bv) * scale);
        }
      } else {
        bf16x4 o4 = {(__bf16)(acc[mt][nt][0] + bv), (__bf16)(acc[mt][nt][1] + bv),
                     (__bf16)(acc[mt][nt][2] + bv), (__bf16)(acc[mt][nt][3] + bv)};
        *(bf16x4*)(&C[((size_t)(bb * 16 + h) << 16) + (size_t)dd * 1024 + nr0]) = o4;
      }
    }
  }
}

// ---------------------------------------------------------------------------
// Fallback QKV (small-ws): 128x128 tile, BK=64, grid 768.  fp32-W path.
// ---------------------------------------------------------------------------
template <bool WBF16>
__global__ __launch_bounds__(256, 3) void gemm_qkv(const __bf16* __restrict__ A,
                                                   const void* __restrict__ Wqp,
                                                   const void* __restrict__ Wkp,
                                                   const void* __restrict__ Wvp,
                                                   const float* __restrict__ bq,
                                                   const float* __restrict__ bk,
                                                   const float* __restrict__ bv,
                                                   __bf16* __restrict__ Qw,
                                                   __bf16* __restrict__ Kw,
                                                   __bf16* __restrict__ Vw) {
  constexpr int BST = WBF16 ? 64 : 72;
  __shared__ __attribute__((aligned(16))) __bf16 As[128][64];
  __shared__ __attribute__((aligned(16))) __bf16 Bs[128 * BST];

  const int tid = threadIdx.x;
  const int lane = tid & 63, w = tid >> 6;
  const int wm = w >> 1, wn = w & 1;
  const int l15 = lane & 15, lq = lane >> 4;
  const int lr = lane >> 3, lc = lane & 7;
  const int xs = l15 & 7;

  const int bid = blockIdx.x;
  const int c = bid & 7, t = bid >> 3;
  const int z = t >> 5;
  const int r = t & 31;
  const int nb = r & 7;
  const int mb = c * 4 + (r >> 3);
  const int m0 = mb * 128, n0 = nb * 128;

  const void* Wp = (z == 0) ? Wqp : (z == 1) ? Wkp : Wvp;
  const float* bias = (z == 0) ? bq : (z == 1) ? bk : bv;
  __bf16* C = (z == 0) ? Qw : (z == 1) ? Kw : Vw;
  const float scale = (z == 0) ? LOG2E : 1.0f;

  f32x4 acc[4][4] = {};

  for (int k0 = 0; k0 < 1024; k0 += 64) {
#pragma unroll
    for (int i = 0; i < 4; ++i) {
      const int row = w * 32 + i * 8 + lr;
      glds16(A + (size_t)(m0 + row) * 1024 + k0 + ((lc ^ lr) * 8), &As[row][lc * 8]);
    }
    if (WBF16) {
      const __bf16* Wb = (const __bf16*)Wp;
#pragma unroll
      for (int i = 0; i < 4; ++i) {
        const int row = w * 32 + i * 8 + lr;
        glds16(Wb + (size_t)(n0 + row) * 1024 + k0 + ((lc ^ lr) * 8), &Bs[row * 64 + lc * 8]);
      }
    } else {
      const float* W = (const float*)Wp;
#pragma unroll
      for (int i = 0; i < 8; ++i) {
        const int cc = i * 256 + tid, row = cc >> 4, col = (cc & 15) * 4;
        float4 wv = *(const float4*)(W + (size_t)(n0 + row) * 1024 + k0 + col);
        bf16x4 b4 = {(__bf16)wv.x, (__bf16)wv.y, (__bf16)wv.z, (__bf16)wv.w};
        *(bf16x4*)(&Bs[row * 72 + col]) = b4;
      }
    }
    __syncthreads();
#pragma unroll
    for (int s = 0; s < 2; ++s) {
      bf16x8 af[4], bfv[4];
#pragma unroll
      for (int mt = 0; mt < 4; ++mt)
        af[mt] = *(const bf16x8*)(&As[wm * 64 + mt * 16 + l15][((s * 4 + lq) ^ xs) * 8]);
#pragma unroll
      for (int nt = 0; nt < 4; ++nt) {
        const int row = wn * 64 + nt * 16 + l15;
        if (WBF16)
          bfv[nt] = *(const bf16x8*)(&Bs[row * 64 + (((s * 4 + lq) ^ xs) * 8)]);
        else
          bfv[nt] = *(const bf16x8*)(&Bs[row * 72 + s * 32 + lq * 8]);
      }
#pragma unroll
      for (int mt = 0; mt < 4; ++mt)
#pragma unroll
        for (int nt = 0; nt < 4; ++nt)
          acc[mt][nt] = __builtin_amdgcn_mfma_f32_16x16x32_bf16(
              af[mt], bfv[nt], acc[mt][nt], 0, 0, 0);
    }
    __syncthreads();
  }

#pragma unroll
  for (int mt = 0; mt < 4; ++mt) {
    const int mg_base = m0 + wm * 64 + mt * 16 + lq * 4;
    const int bb = mg_base >> 10, nr0 = mg_base & 1023;
#pragma unroll
    for (int nt = 0; nt < 4; ++nt) {
      const int ng = n0 + wn * 64 + nt * 16 + l15;
      const float bv = bias[ng];
      const int h = ng >> 6, dd = ng & 63;
      if (z != 2) {
#pragma unroll
        for (int rr = 0; rr < 4; ++rr) {
          const int mg = mg_base + rr;
          const size_t idx =
              ((size_t)(bb * 16 + h) << 16) + (size_t)(mg & 1023) * 64 + dd;
          C[idx] = (__bf16)((acc[mt][nt][rr] + bv) * scale);
        }
      } else {
        bf16x4 o4 = {(__bf16)(acc[mt][nt][0] + bv), (__bf16)(acc[mt][nt][1] + bv),
                     (__bf16)(acc[mt][nt][2] + bv), (__bf16)(acc[mt][nt][3] + bv)};
        *(bf16x4*)(&C[((size_t)(bb * 16 + h) << 16) + (size_t)dd * 1024 + nr0]) = o4;
      }
    }
  }
}

// ---------------------------------------------------------------------------
// Out projection: out[4096,1024] fp32 = O @ Wo^T + bo.  64x128 tile, BK=64,
// 1D grid 512 (2 blocks/CU).  XCD c owns m-blocks c*8..c*8+7, all n (A panel
// 1 MB/XCD L2-local).  4 waves 2x2: wave tile 32x64, acc[2][4].
// ---------------------------------------------------------------------------
__global__ __launch_bounds__(256) void gemm_out(const __bf16* __restrict__ A,
                                                const __bf16* __restrict__ W,
                                                const float* __restrict__ bias,
                                                float* __restrict__ C) {
  __shared__ __attribute__((aligned(16))) __bf16 As[64][64];
  __shared__ __attribute__((aligned(16))) __bf16 Bs[128][64];

  const int tid = threadIdx.x;
  const int lane = tid & 63, w = tid >> 6;
  const int wm = w >> 1, wn = w & 1;
  const int l15 = lane & 15, lq = lane >> 4;
  const int lr = lane >> 3, lc = lane & 7;
  const int xs = l15 & 7;

  const int bid = blockIdx.x;
  const int c = bid & 7, t = bid >> 3;  // c = XCD, t = 0..63
  const int mb = c * 8 + (t & 7);       // 0..63
  const int nb = t >> 3;                // 0..7
  const int m0 = mb * 64, n0 = nb * 128;

  f32x4 acc[2][4] = {};

  for (int k0 = 0; k0 < 1024; k0 += 64) {
#pragma unroll
    for (int i = 0; i < 2; ++i) {  // A: wave w stages rows w*16..+15
      const int row = w * 16 + i * 8 + lr;
      glds16(A + (size_t)(m0 + row) * 1024 + k0 + ((lc ^ lr) * 8), &As[row][lc * 8]);
    }
#pragma unroll
    for (int i = 0; i < 4; ++i) {  // B: wave w stages rows w*32..+31
      const int row = w * 32 + i * 8 + lr;
      glds16(W + (size_t)(n0 + row) * 1024 + k0 + ((lc ^ lr) * 8), &Bs[row][lc * 8]);
    }
    __syncthreads();
#pragma unroll
    for (int s = 0; s < 2; ++s) {
      bf16x8 af[2], bfv[4];
#pragma unroll
      for (int mt = 0; mt < 2; ++mt)
        af[mt] = *(const bf16x8*)(&As[wm * 32 + mt * 16 + l15][((s * 4 + lq) ^ xs) * 8]);
#pragma unroll
      for (int nt = 0; nt < 4; ++nt)
        bfv[nt] = *(const bf16x8*)(&Bs[wn * 64 + nt * 16 + l15][((s * 4 + lq) ^ xs) * 8]);
#pragma unroll
      for (int mt = 0; mt < 2; ++mt)
#pragma unroll
        for (int nt = 0; nt < 4; ++nt)
          acc[mt][nt] = __builtin_amdgcn_mfma_f32_16x16x32_bf16(
              af[mt], bfv[nt], acc[mt][nt], 0, 0, 0);
    }
    __syncthreads();
  }

#pragma unroll
  for (int mt = 0; mt < 2; ++mt) {
    const int mg_base = m0 + wm * 32 + mt * 16 + lq * 4;
#pragma unroll
    for (int nt = 0; nt < 4; ++nt) {
      const int ng = n0 + wn * 64 + nt * 16 + l15;
      const float bv = bias[ng];
#pragma unroll
      for (int r = 0; r < 4; ++r)
        C[(size_t)(mg_base + r) * 1024 + ng] = acc[mt][nt][r] + bv;
    }
  }
}

// ---------------------------------------------------------------------------
// Flash attention, S^T orientation, 32 q per wave (128 q per block, grid
// (bh=64, qt=8) = 512 blocks = 2/CU).  Stage-ahead double-buffer (r15).
// Q pre-scaled by log2(e) -> exp2 softmax.  Reference divides by sqrt(E)=32
// AFTER softmax -> /(l*32).
// ---------------------------------------------------------------------------
__global__ __launch_bounds__(256) void attn_kernel(const __bf16* __restrict__ Q,
                                                   const __bf16* __restrict__ K,
                                                   const __bf16* __restrict__ Vt,
                                                   __bf16* __restrict__ O) {
  __shared__ __attribute__((aligned(16))) __bf16 Ks[2][64][64];
  __shared__ __attribute__((aligned(16))) __bf16 Vs[2][64][64];
  // PQ: first acts as Q staging [128][64] (16 KB), then as P [4][32][72] (18 KB)
  __shared__ __attribute__((aligned(16))) __bf16 PQ[9216];

  __bf16(*Qst)[64] = (__bf16(*)[64])PQ;        // [128][64]
  __bf16(*Ps)[32][72] = (__bf16(*)[32][72])PQ;  // [4][32][72]

  const int tid = threadIdx.x;
  const int lane = tid & 63, w = tid >> 6;
  const int l15 = lane & 15, lq = lane >> 4;
  const int lr = lane >> 3, lc = lane & 7;
  const int xs = l15 & 7;

  const int bh = blockIdx.x;  // 0..63  (same-head blocks share an XCD)
  const int qt = blockIdx.y;  // 0..7
  const __bf16* Qh = Q + (size_t)bh * 65536;
  const __bf16* Kh = K + (size_t)bh * 65536;
  const __bf16* Vh = Vt + (size_t)bh * 65536;

  // prologue: stage Q tile (128x64) + K/V tile kb=0 into buf 0
#pragma unroll
  for (int i = 0; i < 4; ++i) {
    const int row = w * 32 + i * 8 + lr;
    glds16(Qh + (size_t)(qt * 128 + row) * 64 + ((lc ^ lr) * 8), &Qst[row][lc * 8]);
  }
#pragma unroll
  for (int i = 0; i < 2; ++i) {
    const int row = w * 16 + i * 8 + lr;
    glds16(Kh + (size_t)row * 64 + ((lc ^ lr) * 8), &Ks[0][row][lc * 8]);
    glds16(Vh + (size_t)row * 1024 + ((lc ^ lr) * 8), &Vs[0][row][lc * 8]);
  }
  __syncthreads();  // drain all prologue glds
  bf16x8 bqr[2][2];  // [nq][s]
#pragma unroll
  for (int nq = 0; nq < 2; ++nq)
#pragma unroll
    for (int s = 0; s < 2; ++s)
      bqr[nq][s] = *(const bf16x8*)(&Qst[w * 32 + nq * 16 + l15][((s * 4 + lq) ^ xs) * 8]);
  __syncthreads();  // all waves done reading Qst before PQ reused as Ps

  float l_run[2] = {0.0f, 0.0f};
  f32x4 oacc[2][4] = {};

  int buf = 0;
  for (int kb = 0; kb < 16; ++kb) {
    // issue-ahead: stage K/V for kb+1 into buf^1 (in flight during compute)
    if (kb < 15) {
#pragma unroll
      for (int i = 0; i < 2; ++i) {
        const int row = w * 16 + i * 8 + lr;
        glds16(Kh + (size_t)(kb + 1) * 4096 + (size_t)row * 64 + ((lc ^ lr) * 8),
               &Ks[buf ^ 1][row][lc * 8]);
        glds16(Vh + (size_t)row * 1024 + (kb + 1) * 64 + ((lc ^ lr) * 8),
               &Vs[buf ^ 1][row][lc * 8]);
      }
    }

    // S^T: rows = kseq(64), cols = this wave's 32 q (2 frags of 16)
    f32x4 sacc[2][4] = {};
    __builtin_amdgcn_s_setprio(1);
#pragma unroll
    for (int s = 0; s < 2; ++s) {
#pragma unroll
      for (int mt = 0; mt < 4; ++mt) {
        bf16x8 ak = *(const bf16x8*)(&Ks[buf][mt * 16 + l15][((s * 4 + lq) ^ xs) * 8]);
#pragma unroll
        for (int nq = 0; nq < 2; ++nq)
          sacc[nq][mt] = __builtin_amdgcn_mfma_f32_16x16x32_bf16(
              ak, bqr[nq][s], sacc[nq][mt], 0, 0, 0);
      }
    }
    __builtin_amdgcn_s_setprio(0);

    // softmax numerator via exp2 (per-lane q = w*32 + nq*16 + l15)
#pragma unroll
    for (int nq = 0; nq < 2; ++nq) {
      float sum = 0.0f;
#pragma unroll
      for (int mt = 0; mt < 4; ++mt)
#pragma unroll
        for (int r = 0; r < 4; ++r) {
          const float e = __builtin_amdgcn_exp2f(sacc[nq][mt][r]);
          sacc[nq][mt][r] = e;
          sum += e;
        }
      sum += __shfl_xor(sum, 16, 64);
      sum += __shfl_xor(sum, 32, 64);
      l_run[nq] += sum;
    }

    // P -> LDS row-major [q][k] (padded), lane writes 4 consecutive k (b64)
#pragma unroll
    for (int nq = 0; nq < 2; ++nq)
#pragma unroll
      for (int mt = 0; mt < 4; ++mt) {
        bf16x4 p4 = {(__bf16)sacc[nq][mt][0], (__bf16)sacc[nq][mt][1],
                     (__bf16)sacc[nq][mt][2], (__bf16)sacc[nq][mt][3]};
        *(bf16x4*)(&Ps[w][nq * 16 + l15][mt * 16 + lq * 4]) = p4;
      }
    __threadfence_block();  // wave-private P round-trip

    // O^T += Vt · P
    __builtin_amdgcn_s_setprio(1);
#pragma unroll
    for (int s = 0; s < 2; ++s) {
      bf16x8 bp[2];
#pragma unroll
      for (int nq = 0; nq < 2; ++nq)
        bp[nq] = *(const bf16x8*)(&Ps[w][nq * 16 + l15][s * 32 + lq * 8]);
#pragma unroll
      for (int mt = 0; mt < 4; ++mt) {
        bf16x8 av = *(const bf16x8*)(&Vs[buf][mt * 16 + l15][((s * 4 + lq) ^ xs) * 8]);
#pragma unroll
        for (int nq = 0; nq < 2; ++nq)
          oacc[nq][mt] = __builtin_amdgcn_mfma_f32_16x16x32_bf16(
              av, bp[nq], oacc[nq][mt], 0, 0, 0);
      }
    }
    __builtin_amdgcn_s_setprio(0);

    // one barrier: drains this wave's issue-ahead glds (vmcnt) + joins waves
    __syncthreads();
    buf ^= 1;
  }

  // epilogue: O^T col=q(l15), row=d=mt*16+lq*4+r; write O[b*1024+q][h*64+d]
  const int b = bh >> 4, h = bh & 15;
#pragma unroll
  for (int nq = 0; nq < 2; ++nq) {
    const float inv = 1.0f / (l_run[nq] * 32.0f);
    const size_t base =
        (size_t)(b * 1024 + qt * 128 + w * 32 + nq * 16 + l15) * 1024 + h * 64;
#pragma unroll
    for (int mt = 0; mt < 4; ++mt) {
      bf16x4 o4 = {(__bf16)(oacc[nq][mt][0] * inv), (__bf16)(oacc[nq][mt][1] * inv),
                   (__bf16)(oacc[nq][mt][2] * inv), (__bf16)(oacc[nq][mt][3] * inv)};
      *(bf16x4*)(&O[base + mt * 16 + lq * 4]) = o4;
    }
  }
}

// ---------------------------------------------------------------------------
extern "C" void kernel_launch(void* const* d_in, const int* in_sizes, int n_in,
                              void* d_out, int out_size, void* d_ws, size_t ws_size,
                              hipStream_t stream) {
  const float* x  = (const float*)d_in[0];
  const float* Wq = (const float*)d_in[1];
  const float* bq = (const float*)d_in[2];
  const float* Wk = (const float*)d_in[3];
  const float* bk = (const float*)d_in[4];
  const float* Wv = (const float*)d_in[5];
  const float* bv = (const float*)d_in[6];
  const float* Wo = (const float*)d_in[7];
  const float* bo = (const float*)d_in[8];
  float* out = (float*)d_out;

  const size_t SZ = (size_t)4 * 1024 * 1024;  // 4M bf16 per slot (8 MB)
  __bf16* Qw = (__bf16*)d_ws;
  __bf16* Kw = Qw + SZ;
  __bf16* Vw = Kw + SZ;
  __bf16* s3 = Vw + SZ;  // xb during QKV, then Ow
  __bf16* xb = s3;
  __bf16* Ow = s3;

  dim3 blk(256);

  if (ws_size >= (size_t)40 * 1024 * 1024) {
    __bf16* Wqb = s3 + SZ;  // 2 MB each
    __bf16* Wkb = Wqb + SZ / 4;
    __bf16* Wvb = Wkb + SZ / 4;
    __bf16* Wob = Wvb + SZ / 4;
    static bool attr_set = false;
    if (!attr_set) {
      (void)hipFuncSetAttribute((const void*)gemm_qkv8,
                                hipFuncAttributeMaxDynamicSharedMemorySize, 131072);
      attr_set = true;
    }
    cvt_all<<<8192, blk, 0, stream>>>(x, Wq, Wk, Wv, Wo, xb, Wqb, Wkb, Wvb, Wob);
    gemm_qkv8<<<dim3(192), dim3(512), 131072, stream>>>(xb, Wqb, Wkb, Wvb,
                                                        bq, bk, bv, Qw, Kw, Vw);
    attn_kernel<<<dim3(64, 8), blk, 0, stream>>>(Qw, Kw, Vw, Ow);
    gemm_out<<<dim3(512), blk, 0, stream>>>(Ow, Wob, bo, out);
  } else {
    __bf16* Wob = Kw;  // Kw dead after attention
    cvt_f32_bf16<<<4096, blk, 0, stream>>>(x, xb, 1048576);
    gemm_qkv<false><<<dim3(768), blk, 0, stream>>>(xb, Wq, Wk, Wv,
                                                   bq, bk, bv, Qw, Kw, Vw);
    attn_kernel<<<dim3(64, 8), blk, 0, stream>>>(Qw, Kw, Vw, Ow);
    cvt_f32_bf16<<<1024, blk, 0, stream>>>(Wo, Wob, 262144);
    gemm_out<<<dim3(512), blk, 0, stream>>>(Ow, Wob, bo, out);
  }
}

// Round 5
// 158.865 us; speedup vs baseline: 1.1130x; 1.1130x over previous
//
#include <hip/hip_runtime.h>
#include <hip/hip_bf16.h>

// MHA: B=4, N=1024, E=1024, H=16, d=64.  fp32 I/O, bf16 MFMA internals.
//
// Round 17: (1) qkv8 reverted -> r13 128x128 gemm_qkv (0 bank conflicts,
// ~31 us; r16's BK=32 ring had 64B rows -> 4-way ds_read conflicts, 2.36M).
// (2) attn + gemm_out: ring-3 prefetch-distance-2 with counted vmcnt
// (vmcnt(N)->s_barrier->issue slot kb+2->compute slot kb; vmcnt never 0
// until tail).  Dynamic LDS (attn 66 KB, out 72 KB) via hipFuncSetAttribute;
// both stay 2 blocks/CU.  Proven 64-col XOR swizzle layouts kept everywhere.
//
// XOR-swizzled [row][64] LDS tiles: LDS[row][c8] holds G[row][c8 ^ (row&7)];
// frag readers XOR with l15&7.  Staging via global_load_lds(16B).
//
// ws (40 MB fast path): [Qw 8M][Kw 8M][Vw 8M][xb/Ow 8M][Wqb][Wkb][Wvb][Wob]
// (2 MB each).  ws_size < 40 MB -> fp32-W fallback (deterministic branch).
//
// MFMA m89/m91 layouts: A-frag A[m=l&15][k=(l>>4)*8+j]; B-frag same addressing
// from row-major [n][k]; C/D col=l&15, row=(l>>4)*4+reg.

typedef __bf16 bf16x8 __attribute__((ext_vector_type(8)));
typedef __bf16 bf16x4 __attribute__((ext_vector_type(4)));
typedef float  f32x4  __attribute__((ext_vector_type(4)));

#define LOG2E 1.44269504f

__device__ __forceinline__ void glds16(const __bf16* g, __bf16* l) {
  __builtin_amdgcn_global_load_lds(
      (const __attribute__((address_space(1))) void*)g,
      (__attribute__((address_space(3))) void*)l, 16, 0, 0);
}

__global__ __launch_bounds__(256) void cvt_f32_bf16(const float* __restrict__ in,
                                                    __bf16* __restrict__ out, int n4) {
  int i = blockIdx.x * 256 + threadIdx.x;
  if (i < n4) {
    float4 v = *(const float4*)(in + (size_t)i * 4);
    bf16x4 b = {(__bf16)v.x, (__bf16)v.y, (__bf16)v.z, (__bf16)v.w};
    *(bf16x4*)(out + (size_t)i * 4) = b;
  }
}

// Fused conversion: x (1M float4) + Wq/Wk/Wv/Wo (256K float4 each).
__global__ __launch_bounds__(256) void cvt_all(const float* __restrict__ x,
                                               const float* __restrict__ Wq,
                                               const float* __restrict__ Wk,
                                               const float* __restrict__ Wv,
                                               const float* __restrict__ Wo,
                                               __bf16* __restrict__ xb,
                                               __bf16* __restrict__ Wqb,
                                               __bf16* __restrict__ Wkb,
                                               __bf16* __restrict__ Wvb,
                                               __bf16* __restrict__ Wob) {
  const int i = blockIdx.x * 256 + threadIdx.x;  // 0..2097151
  const float* src;
  __bf16* dst;
  int off;
  if (i < 1048576) {
    src = x; dst = xb; off = i;
  } else {
    const int j = i - 1048576;
    const int seg = j >> 18;  // 0..3
    off = j & 262143;
    src = (seg == 0) ? Wq : (seg == 1) ? Wk : (seg == 2) ? Wv : Wo;
    dst = (seg == 0) ? Wqb : (seg == 1) ? Wkb : (seg == 2) ? Wvb : Wob;
  }
  float4 v = *(const float4*)(src + (size_t)off * 4);
  bf16x4 b = {(__bf16)v.x, (__bf16)v.y, (__bf16)v.z, (__bf16)v.w};
  *(bf16x4*)(dst + (size_t)off * 4) = b;
}

// ---------------------------------------------------------------------------
// Fused QKV projection, 128x128 tile, BK=64, 1D grid 768 (3 blocks/CU).
// XCD decomposition: c=bid&7 -> XCD c owns m-blocks c*4..c*4+3 for all z,nb.
// z=0/1/2 -> Q/K (head layout [b,h,n,d]), V (transposed [b,h,d,n]).
// Q epilogue scaled by log2(e) so attn can use exp2 directly.
// ---------------------------------------------------------------------------
template <bool WBF16>
__global__ __launch_bounds__(256, 3) void gemm_qkv(const __bf16* __restrict__ A,
                                                   const void* __restrict__ Wqp,
                                                   const void* __restrict__ Wkp,
                                                   const void* __restrict__ Wvp,
                                                   const float* __restrict__ bq,
                                                   const float* __restrict__ bk,
                                                   const float* __restrict__ bv,
                                                   __bf16* __restrict__ Qw,
                                                   __bf16* __restrict__ Kw,
                                                   __bf16* __restrict__ Vw) {
  constexpr int BST = WBF16 ? 64 : 72;
  __shared__ __attribute__((aligned(16))) __bf16 As[128][64];
  __shared__ __attribute__((aligned(16))) __bf16 Bs[128 * BST];

  const int tid = threadIdx.x;
  const int lane = tid & 63, w = tid >> 6;
  const int wm = w >> 1, wn = w & 1;
  const int l15 = lane & 15, lq = lane >> 4;
  const int lr = lane >> 3, lc = lane & 7;
  const int xs = l15 & 7;

  const int bid = blockIdx.x;
  const int c = bid & 7, t = bid >> 3;
  const int z = t >> 5;
  const int r = t & 31;
  const int nb = r & 7;
  const int mb = c * 4 + (r >> 3);
  const int m0 = mb * 128, n0 = nb * 128;

  const void* Wp = (z == 0) ? Wqp : (z == 1) ? Wkp : Wvp;
  const float* bias = (z == 0) ? bq : (z == 1) ? bk : bv;
  __bf16* C = (z == 0) ? Qw : (z == 1) ? Kw : Vw;
  const float scale = (z == 0) ? LOG2E : 1.0f;

  f32x4 acc[4][4] = {};

  for (int k0 = 0; k0 < 1024; k0 += 64) {
#pragma unroll
    for (int i = 0; i < 4; ++i) {
      const int row = w * 32 + i * 8 + lr;
      glds16(A + (size_t)(m0 + row) * 1024 + k0 + ((lc ^ lr) * 8), &As[row][lc * 8]);
    }
    if (WBF16) {
      const __bf16* Wb = (const __bf16*)Wp;
#pragma unroll
      for (int i = 0; i < 4; ++i) {
        const int row = w * 32 + i * 8 + lr;
        glds16(Wb + (size_t)(n0 + row) * 1024 + k0 + ((lc ^ lr) * 8), &Bs[row * 64 + lc * 8]);
      }
    } else {
      const float* W = (const float*)Wp;
#pragma unroll
      for (int i = 0; i < 8; ++i) {
        const int cc = i * 256 + tid, row = cc >> 4, col = (cc & 15) * 4;
        float4 wv = *(const float4*)(W + (size_t)(n0 + row) * 1024 + k0 + col);
        bf16x4 b4 = {(__bf16)wv.x, (__bf16)wv.y, (__bf16)wv.z, (__bf16)wv.w};
        *(bf16x4*)(&Bs[row * 72 + col]) = b4;
      }
    }
    __syncthreads();
#pragma unroll
    for (int s = 0; s < 2; ++s) {
      bf16x8 af[4], bfv[4];
#pragma unroll
      for (int mt = 0; mt < 4; ++mt)
        af[mt] = *(const bf16x8*)(&As[wm * 64 + mt * 16 + l15][((s * 4 + lq) ^ xs) * 8]);
#pragma unroll
      for (int nt = 0; nt < 4; ++nt) {
        const int row = wn * 64 + nt * 16 + l15;
        if (WBF16)
          bfv[nt] = *(const bf16x8*)(&Bs[row * 64 + (((s * 4 + lq) ^ xs) * 8)]);
        else
          bfv[nt] = *(const bf16x8*)(&Bs[row * 72 + s * 32 + lq * 8]);
      }
#pragma unroll
      for (int mt = 0; mt < 4; ++mt)
#pragma unroll
        for (int nt = 0; nt < 4; ++nt)
          acc[mt][nt] = __builtin_amdgcn_mfma_f32_16x16x32_bf16(
              af[mt], bfv[nt], acc[mt][nt], 0, 0, 0);
    }
    __syncthreads();
  }

#pragma unroll
  for (int mt = 0; mt < 4; ++mt) {
    const int mg_base = m0 + wm * 64 + mt * 16 + lq * 4;
    const int bb = mg_base >> 10, nr0 = mg_base & 1023;
#pragma unroll
    for (int nt = 0; nt < 4; ++nt) {
      const int ng = n0 + wn * 64 + nt * 16 + l15;
      const float bv = bias[ng];
      const int h = ng >> 6, dd = ng & 63;
      if (z != 2) {
#pragma unroll
        for (int rr = 0; rr < 4; ++rr) {
          const int mg = mg_base + rr;
          const size_t idx =
              ((size_t)(bb * 16 + h) << 16) + (size_t)(mg & 1023) * 64 + dd;
          C[idx] = (__bf16)((acc[mt][nt][rr] + bv) * scale);
        }
      } else {
        bf16x4 o4 = {(__bf16)(acc[mt][nt][0] + bv), (__bf16)(acc[mt][nt][1] + bv),
                     (__bf16)(acc[mt][nt][2] + bv), (__bf16)(acc[mt][nt][3] + bv)};
        *(bf16x4*)(&C[((size_t)(bb * 16 + h) << 16) + (size_t)dd * 1024 + nr0]) = o4;
      }
    }
  }
}

// ---------------------------------------------------------------------------
// Out projection: out[4096,1024] fp32 = O @ Wo^T + bo.  64x128 tile, BK=64,
// 1D grid 512, XCD-mapped.  Ring-3 prefetch-distance-2, counted vmcnt:
// top of iter kb: vmcnt(6) [slot kb landed; kb+1,kb+2 in flight] -> s_barrier
// [slot (kb+2)%3 free] -> issue slot kb+2 -> compute slot kb.  6 glds/slot
// per wave (A 2 + B 4).  Dynamic LDS 72 KB (3 x (A 8K + B 16K)) -> 2/CU.
// ---------------------------------------------------------------------------
__global__ __launch_bounds__(256, 2) void gemm_out(const __bf16* __restrict__ A,
                                                   const __bf16* __restrict__ W,
                                                   const float* __restrict__ bias,
                                                   float* __restrict__ C) {
  extern __shared__ __attribute__((aligned(16))) __bf16 lds_o[];
  __bf16(*As)[64][64] = (__bf16(*)[64][64])lds_o;              // 3 x 4096
  __bf16(*Bs)[128][64] = (__bf16(*)[128][64])(lds_o + 12288);  // 3 x 8192

  const int tid = threadIdx.x;
  const int lane = tid & 63, w = tid >> 6;
  const int wm = w >> 1, wn = w & 1;
  const int l15 = lane & 15, lq = lane >> 4;
  const int lr = lane >> 3, lc = lane & 7;
  const int xs = l15 & 7;

  const int bid = blockIdx.x;
  const int c = bid & 7, t = bid >> 3;  // c = XCD, t = 0..63
  const int mb = c * 8 + (t & 7);       // 0..63
  const int nb = t >> 3;                // 0..7
  const int m0 = mb * 64, n0 = nb * 128;

  auto stage = [&](int kb, int sl) {
    const int k0 = kb * 64;
#pragma unroll
    for (int i = 0; i < 2; ++i) {  // A: wave w rows w*16..+15
      const int row = w * 16 + i * 8 + lr;
      glds16(A + (size_t)(m0 + row) * 1024 + k0 + ((lc ^ lr) * 8), &As[sl][row][lc * 8]);
    }
#pragma unroll
    for (int i = 0; i < 4; ++i) {  // B: wave w rows w*32..+31
      const int row = w * 32 + i * 8 + lr;
      glds16(W + (size_t)(n0 + row) * 1024 + k0 + ((lc ^ lr) * 8), &Bs[sl][row][lc * 8]);
    }
  };

  f32x4 acc[2][4] = {};

  stage(0, 0);
  stage(1, 1);

  for (int kb = 0; kb < 16; ++kb) {
    if (kb < 15)
      asm volatile("s_waitcnt vmcnt(6)" ::: "memory");
    else
      asm volatile("s_waitcnt vmcnt(0)" ::: "memory");
    __builtin_amdgcn_s_barrier();
    if (kb < 14) stage(kb + 2, (kb + 2) % 3);

    const int sl = kb % 3;
#pragma unroll
    for (int s = 0; s < 2; ++s) {
      bf16x8 af[2], bfv[4];
#pragma unroll
      for (int mt = 0; mt < 2; ++mt)
        af[mt] = *(const bf16x8*)(&As[sl][wm * 32 + mt * 16 + l15][((s * 4 + lq) ^ xs) * 8]);
#pragma unroll
      for (int nt = 0; nt < 4; ++nt)
        bfv[nt] = *(const bf16x8*)(&Bs[sl][wn * 64 + nt * 16 + l15][((s * 4 + lq) ^ xs) * 8]);
      __builtin_amdgcn_s_setprio(1);
#pragma unroll
      for (int mt = 0; mt < 2; ++mt)
#pragma unroll
        for (int nt = 0; nt < 4; ++nt)
          acc[mt][nt] = __builtin_amdgcn_mfma_f32_16x16x32_bf16(
              af[mt], bfv[nt], acc[mt][nt], 0, 0, 0);
      __builtin_amdgcn_s_setprio(0);
    }
  }

#pragma unroll
  for (int mt = 0; mt < 2; ++mt) {
    const int mg_base = m0 + wm * 32 + mt * 16 + lq * 4;
#pragma unroll
    for (int nt = 0; nt < 4; ++nt) {
      const int ng = n0 + wn * 64 + nt * 16 + l15;
      const float bv = bias[ng];
#pragma unroll
      for (int r = 0; r < 4; ++r)
        C[(size_t)(mg_base + r) * 1024 + ng] = acc[mt][nt][r] + bv;
    }
  }
}

// ---------------------------------------------------------------------------
// Flash attention, S^T orientation, 32 q per wave (128 q per block, grid
// (bh=64, qt=8) = 512 blocks = 2/CU).  Ring-3 prefetch-distance-2 K/V with
// counted vmcnt: top of iter kb: vmcnt(4) [slot kb landed; kb+1,kb+2 in
// flight] -> s_barrier -> issue slot kb+2 -> compute slot kb.  4 glds/slot
// per wave (K 2 + V 2).  Q fragments register-hoisted; Q-stage LDS reused as
// P buffer.  Q pre-scaled by log2(e) -> exp2 softmax.  Reference divides by
// sqrt(E)=32 AFTER softmax -> /(l*32).  Dynamic LDS 66 KB -> 2/CU.
// ---------------------------------------------------------------------------
__global__ __launch_bounds__(256, 2) void attn_kernel(const __bf16* __restrict__ Q,
                                                      const __bf16* __restrict__ K,
                                                      const __bf16* __restrict__ Vt,
                                                      __bf16* __restrict__ O) {
  extern __shared__ __attribute__((aligned(16))) __bf16 lds_a[];
  __bf16(*Ks)[64][64] = (__bf16(*)[64][64])lds_a;               // 3 x 4096
  __bf16(*Vs)[64][64] = (__bf16(*)[64][64])(lds_a + 12288);     // 3 x 4096
  __bf16* PQ = lds_a + 24576;                                   // 9216 elems
  __bf16(*Qst)[64] = (__bf16(*)[64])PQ;                         // [128][64]
  __bf16(*Ps)[32][72] = (__bf16(*)[32][72])PQ;                  // [4][32][72]

  const int tid = threadIdx.x;
  const int lane = tid & 63, w = tid >> 6;
  const int l15 = lane & 15, lq = lane >> 4;
  const int lr = lane >> 3, lc = lane & 7;
  const int xs = l15 & 7;

  const int bh = blockIdx.x;  // 0..63  (same-head blocks share an XCD)
  const int qt = blockIdx.y;  // 0..7
  const __bf16* Qh = Q + (size_t)bh * 65536;
  const __bf16* Kh = K + (size_t)bh * 65536;
  const __bf16* Vh = Vt + (size_t)bh * 65536;

  auto stage_kv = [&](int kb, int sl) {
#pragma unroll
    for (int i = 0; i < 2; ++i) {
      const int row = w * 16 + i * 8 + lr;
      glds16(Kh + (size_t)kb * 4096 + (size_t)row * 64 + ((lc ^ lr) * 8),
             &Ks[sl][row][lc * 8]);
      glds16(Vh + (size_t)row * 1024 + kb * 64 + ((lc ^ lr) * 8),
             &Vs[sl][row][lc * 8]);
    }
  };

  // prologue: stage Q tile (128x64) + K/V slot 0
#pragma unroll
  for (int i = 0; i < 4; ++i) {
    const int row = w * 32 + i * 8 + lr;
    glds16(Qh + (size_t)(qt * 128 + row) * 64 + ((lc ^ lr) * 8), &Qst[row][lc * 8]);
  }
  stage_kv(0, 0);
  __syncthreads();  // drain Q + slot0 glds for all waves
  bf16x8 bqr[2][2];  // [nq][s]
#pragma unroll
  for (int nq = 0; nq < 2; ++nq)
#pragma unroll
    for (int s = 0; s < 2; ++s)
      bqr[nq][s] = *(const bf16x8*)(&Qst[w * 32 + nq * 16 + l15][((s * 4 + lq) ^ xs) * 8]);
  __syncthreads();  // all waves done reading Qst before PQ reused as Ps
  stage_kv(1, 1);   // distance-2 pipeline primed (4 loads in flight)

  float l_run[2] = {0.0f, 0.0f};
  f32x4 oacc[2][4] = {};

  for (int kb = 0; kb < 16; ++kb) {
    if (kb < 15)
      asm volatile("s_waitcnt vmcnt(4)" ::: "memory");
    else
      asm volatile("s_waitcnt vmcnt(0)" ::: "memory");
    __builtin_amdgcn_s_barrier();
    if (kb < 14) stage_kv(kb + 2, (kb + 2) % 3);
    const int sl = kb % 3;

    // S^T: rows = kseq(64), cols = this wave's 32 q (2 frags of 16)
    f32x4 sacc[2][4] = {};
    __builtin_amdgcn_s_setprio(1);
#pragma unroll
    for (int s = 0; s < 2; ++s) {
#pragma unroll
      for (int mt = 0; mt < 4; ++mt) {
        bf16x8 ak = *(const bf16x8*)(&Ks[sl][mt * 16 + l15][((s * 4 + lq) ^ xs) * 8]);
#pragma unroll
        for (int nq = 0; nq < 2; ++nq)
          sacc[nq][mt] = __builtin_amdgcn_mfma_f32_16x16x32_bf16(
              ak, bqr[nq][s], sacc[nq][mt], 0, 0, 0);
      }
    }
    __builtin_amdgcn_s_setprio(0);

    // softmax numerator via exp2 (per-lane q = w*32 + nq*16 + l15)
#pragma unroll
    for (int nq = 0; nq < 2; ++nq) {
      float sum = 0.0f;
#pragma unroll
      for (int mt = 0; mt < 4; ++mt)
#pragma unroll
        for (int r = 0; r < 4; ++r) {
          const float e = __builtin_amdgcn_exp2f(sacc[nq][mt][r]);
          sacc[nq][mt][r] = e;
          sum += e;
        }
      sum += __shfl_xor(sum, 16, 64);
      sum += __shfl_xor(sum, 32, 64);
      l_run[nq] += sum;
    }

    // P -> LDS row-major [q][k] (padded), lane writes 4 consecutive k (b64)
#pragma unroll
    for (int nq = 0; nq < 2; ++nq)
#pragma unroll
      for (int mt = 0; mt < 4; ++mt) {
        bf16x4 p4 = {(__bf16)sacc[nq][mt][0], (__bf16)sacc[nq][mt][1],
                     (__bf16)sacc[nq][mt][2], (__bf16)sacc[nq][mt][3]};
        *(bf16x4*)(&Ps[w][nq * 16 + l15][mt * 16 + lq * 4]) = p4;
      }
    __threadfence_block();  // wave-private P round-trip

    // O^T += Vt · P
    __builtin_amdgcn_s_setprio(1);
#pragma unroll
    for (int s = 0; s < 2; ++s) {
      bf16x8 bp[2];
#pragma unroll
      for (int nq = 0; nq < 2; ++nq)
        bp[nq] = *(const bf16x8*)(&Ps[w][nq * 16 + l15][s * 32 + lq * 8]);
#pragma unroll
      for (int mt = 0; mt < 4; ++mt) {
        bf16x8 av = *(const bf16x8*)(&Vs[sl][mt * 16 + l15][((s * 4 + lq) ^ xs) * 8]);
#pragma unroll
        for (int nq = 0; nq < 2; ++nq)
          oacc[nq][mt] = __builtin_amdgcn_mfma_f32_16x16x32_bf16(
              av, bp[nq], oacc[nq][mt], 0, 0, 0);
      }
    }
    __builtin_amdgcn_s_setprio(0);
    // no trailing barrier: next-iter vmcnt+s_barrier protects ring reuse
  }

  // epilogue: O^T col=q(l15), row=d=mt*16+lq*4+r; write O[b*1024+q][h*64+d]
  const int b = bh >> 4, h = bh & 15;
#pragma unroll
  for (int nq = 0; nq < 2; ++nq) {
    const float inv = 1.0f / (l_run[nq] * 32.0f);
    const size_t base =
        (size_t)(b * 1024 + qt * 128 + w * 32 + nq * 16 + l15) * 1024 + h * 64;
#pragma unroll
    for (int mt = 0; mt < 4; ++mt) {
      bf16x4 o4 = {(__bf16)(oacc[nq][mt][0] * inv), (__bf16)(oacc[nq][mt][1] * inv),
                   (__bf16)(oacc[nq][mt][2] * inv), (__bf16)(oacc[nq][mt][3] * inv)};
      *(bf16x4*)(&O[base + mt * 16 + lq * 4]) = o4;
    }
  }
}

// ---------------------------------------------------------------------------
extern "C" void kernel_launch(void* const* d_in, const int* in_sizes, int n_in,
                              void* d_out, int out_size, void* d_ws, size_t ws_size,
                              hipStream_t stream) {
  const float* x  = (const float*)d_in[0];
  const float* Wq = (const float*)d_in[1];
  const float* bq = (const float*)d_in[2];
  const float* Wk = (const float*)d_in[3];
  const float* bk = (const float*)d_in[4];
  const float* Wv = (const float*)d_in[5];
  const float* bv = (const float*)d_in[6];
  const float* Wo = (const float*)d_in[7];
  const float* bo = (const float*)d_in[8];
  float* out = (float*)d_out;

  const size_t SZ = (size_t)4 * 1024 * 1024;  // 4M bf16 per slot (8 MB)
  __bf16* Qw = (__bf16*)d_ws;
  __bf16* Kw = Qw + SZ;
  __bf16* Vw = Kw + SZ;
  __bf16* s3 = Vw + SZ;  // xb during QKV, then Ow
  __bf16* xb = s3;
  __bf16* Ow = s3;

  dim3 blk(256);

  static bool attr_set = false;
  if (!attr_set) {
    (void)hipFuncSetAttribute((const void*)attn_kernel,
                              hipFuncAttributeMaxDynamicSharedMemorySize, 67584);
    (void)hipFuncSetAttribute((const void*)gemm_out,
                              hipFuncAttributeMaxDynamicSharedMemorySize, 73728);
    attr_set = true;
  }

  if (ws_size >= (size_t)40 * 1024 * 1024) {
    __bf16* Wqb = s3 + SZ;  // 2 MB each
    __bf16* Wkb = Wqb + SZ / 4;
    __bf16* Wvb = Wkb + SZ / 4;
    __bf16* Wob = Wvb + SZ / 4;
    cvt_all<<<8192, blk, 0, stream>>>(x, Wq, Wk, Wv, Wo, xb, Wqb, Wkb, Wvb, Wob);
    gemm_qkv<true><<<dim3(768), blk, 0, stream>>>(xb, Wqb, Wkb, Wvb,
                                                  bq, bk, bv, Qw, Kw, Vw);
    attn_kernel<<<dim3(64, 8), blk, 67584, stream>>>(Qw, Kw, Vw, Ow);
    gemm_out<<<dim3(512), blk, 73728, stream>>>(Ow, Wob, bo, out);
  } else {
    __bf16* Wob = Kw;  // Kw dead after attention
    cvt_f32_bf16<<<4096, blk, 0, stream>>>(x, xb, 1048576);
    gemm_qkv<false><<<dim3(768), blk, 0, stream>>>(xb, Wq, Wk, Wv,
                                                   bq, bk, bv, Qw, Kw, Vw);
    attn_kernel<<<dim3(64, 8), blk, 67584, stream>>>(Qw, Kw, Vw, Ow);
    cvt_f32_bf16<<<1024, blk, 0, stream>>>(Wo, Wob, 262144);
    gemm_out<<<dim3(512), blk, 73728, stream>>>(Ow, Wob, bo, out);
  }
}